// Round 9
// baseline (194.143 us; speedup 1.0000x reference)
//
#include <hip/hip_runtime.h>

#define BATCH 4
#define SEQ   4096
#define EMB   1024
#define HD    64
#define NROW  (BATCH*SEQ)

typedef float f32x4  __attribute__((ext_vector_type(4)));
typedef short bf16x8 __attribute__((ext_vector_type(8)));
typedef short bf16x4 __attribute__((ext_vector_type(4)));

#define LOG2E 1.4426950408889634f
#define EXP2(x) exp2f(x)

static __device__ __forceinline__ f32x4 MFMA16(bf16x4 a, bf16x4 b, f32x4 c) {
#if defined(__HIP_DEVICE_COMPILE__) && __has_builtin(__builtin_amdgcn_mfma_f32_16x16x16bf16_1k)
  return __builtin_amdgcn_mfma_f32_16x16x16bf16_1k(a, b, c, 0, 0, 0);
#elif defined(__HIP_DEVICE_COMPILE__)
  f32x4 d;
  asm volatile("v_mfma_f32_16x16x16_bf16 %0, %1, %2, %3"
               : "=v"(d) : "v"(a), "v"(b), "v"(c));
  return d;
#else
  return c;  // host stub, never executed
#endif
}

static __device__ __forceinline__ short f2bf(float f) {
  union { float f; unsigned u; } v; v.f = f;
  unsigned r = v.u + 0x7fffu + ((v.u >> 16) & 1u);
  return (short)(r >> 16);
}
static __device__ __forceinline__ float bf2f(short s) {
  union { unsigned u; float f; } v; v.u = ((unsigned)(unsigned short)s) << 16;
  return v.f;
}
static __device__ __forceinline__ unsigned cvtpk(float lo, float hi) {
  unsigned r;
  asm("v_cvt_pk_bf16_f32 %0, %1, %2" : "=v"(r) : "v"(lo), "v"(hi));
  return r;
}
static __device__ __forceinline__ float max3f(float a, float b, float c) {
  float r;
  asm("v_max3_f32 %0, %1, %2, %3" : "=v"(r) : "v"(a), "v"(b), "v"(c));
  return r;
}
static __device__ __forceinline__ bf16x4 pack4(unsigned w01, unsigned w23) {
  union { unsigned u[2]; bf16x4 v; } x;
  x.u[0] = w01; x.u[1] = w23;
  return x.v;
}

// ---------------------------------------------------------------------------
// Wtf: fragment-contiguous B layout (unchanged).
// ---------------------------------------------------------------------------
__global__ __launch_bounds__(256) void wt_kernel(
    const float* __restrict__ Wq, const float* __restrict__ Wk,
    const float* __restrict__ Wv, short* __restrict__ Wtf) {
  __shared__ float t[64][65];
  int bid = blockIdx.x;
  int mat = bid >> 4;
  int et  = bid & 15;
  int e0  = et * 64;
  const float* W = (mat == 0) ? Wq : (mat == 1) ? Wk : Wv;
  int c  = threadIdx.x & 63;
  int r0 = threadIdx.x >> 6;
#pragma unroll
  for (int i = 0; i < 16; ++i)
    t[i * 4 + r0][c] = W[(size_t)(e0 + i * 4 + r0) * HD + c];
  __syncthreads();
#pragma unroll
  for (int half = 0; half < 2; ++half) {
    int cid  = half * 256 + threadIdx.x;
    int ct4  = cid >> 7;
    int ksl  = (cid >> 6) & 1;
    int lane = cid & 63;
    int g    = lane >> 4;
    int mi   = lane & 15;
    int ct   = mat * 4 + ct4;
    int ks   = et * 2 + ksl;
    bf16x8 v;
#pragma unroll
    for (int j = 0; j < 8; ++j)
      v[j] = f2bf(t[ksl * 32 + 8 * g + j][ct4 * 16 + mi]);
    *(bf16x8*)(Wtf + ((size_t)(ct * 32 + ks) * 64 + lane) * 8) = v;
  }
}

// ---------------------------------------------------------------------------
// QKV projection (reverted to the R7 version: BM=32, split-K x2, dbuf LDS).
// ---------------------------------------------------------------------------
__global__ __launch_bounds__(256) void qkv_kernel(
    const float* __restrict__ X, const short* __restrict__ Wtf,
    const float* __restrict__ bq, const float* __restrict__ bk, const float* __restrict__ bv,
    short* __restrict__ Qf, short* __restrict__ Kf, short* __restrict__ Vf) {
  __shared__ __align__(16) short xs[2][2][32][32];
  __shared__ float part[2][12][4][64];

  int tid  = threadIdx.x;
  int w    = tid >> 6;
  int lane = tid & 63;
  int g    = lane >> 4;
  int mi   = lane & 15;
  int rs   = w & 1;
  int h    = w >> 1;
  int rowbase = blockIdx.x * 32;

  int sr = tid >> 3;
  int sc = tid & 7;
  const float* xsrc = X + (size_t)(rowbase + sr) * EMB + sc * 4;

  f32x4 acc[12];
#pragma unroll
  for (int i = 0; i < 12; ++i) acc[i] = (f32x4){0.f, 0.f, 0.f, 0.f};

  {
    float4 xa = *(const float4*)(xsrc);
    float4 xb = *(const float4*)(xsrc + 512);
    bf16x4 va, vb;
    va[0] = f2bf(xa.x); va[1] = f2bf(xa.y); va[2] = f2bf(xa.z); va[3] = f2bf(xa.w);
    vb[0] = f2bf(xb.x); vb[1] = f2bf(xb.y); vb[2] = f2bf(xb.z); vb[3] = f2bf(xb.w);
    *(bf16x4*)(&xs[0][0][sr][sc * 4]) = va;
    *(bf16x4*)(&xs[0][1][sr][sc * 4]) = vb;
  }
  __syncthreads();

  const short* wp = Wtf + (size_t)(h * 16) * 512 + lane * 8;

#pragma unroll 2
  for (int ks = 0; ks < 16; ++ks) {
    int buf = ks & 1;
    float4 xa, xb;
    if (ks < 15) {
      xa = *(const float4*)(xsrc + (ks + 1) * 32);
      xb = *(const float4*)(xsrc + (ks + 1) * 32 + 512);
    }
    bf16x8 af = *(const bf16x8*)(&xs[buf][h][rs * 16 + mi][g * 8]);
    const short* wk = wp + ks * 512;
#pragma unroll
    for (int ct = 0; ct < 12; ++ct) {
      bf16x8 bfr = *(const bf16x8*)(wk + (size_t)ct * 16384);
      acc[ct] = __builtin_amdgcn_mfma_f32_16x16x32_bf16(af, bfr, acc[ct], 0, 0, 0);
    }
    if (ks < 15) {
      bf16x4 va, vb;
      va[0] = f2bf(xa.x); va[1] = f2bf(xa.y); va[2] = f2bf(xa.z); va[3] = f2bf(xa.w);
      vb[0] = f2bf(xb.x); vb[1] = f2bf(xb.y); vb[2] = f2bf(xb.z); vb[3] = f2bf(xb.w);
      *(bf16x4*)(&xs[buf ^ 1][0][sr][sc * 4]) = va;
      *(bf16x4*)(&xs[buf ^ 1][1][sr][sc * 4]) = vb;
    }
    __syncthreads();
  }

  if (h == 1) {
#pragma unroll
    for (int ct = 0; ct < 12; ++ct)
#pragma unroll
      for (int r = 0; r < 4; ++r) part[rs][ct][r][lane] = acc[ct][r];
  }
  __syncthreads();
  if (h == 0) {
#pragma unroll
    for (int ct = 0; ct < 12; ++ct)
#pragma unroll
      for (int r = 0; r < 4; ++r) part[rs][ct][r][lane] += acc[ct][r];
  }
  __syncthreads();

  int b_  = rowbase >> 12;                 // batch
  int srb = rowbase & (SEQ - 1);           // row within batch

  // Qf / Kf fragment-packed stores: thread = (tl, kh, lane)
  {
    int tl  = tid >> 7;
    int kh  = (tid >> 6) & 1;
    int ln  = tid & 63;
    int gg  = ln >> 4;
    int mi2 = ln & 15;
    int tgl = (srb >> 4) + tl;             // tile within batch
    bf16x8 vq, vk;
#pragma unroll
    for (int j = 0; j < 8; ++j) {
      int hd = kh * 32 + 8 * gg + j;
      int ct = hd >> 4, cc = hd & 15;
      int li = (mi2 >> 2) * 16 + cc;
      int r2 = mi2 & 3;
      vq[j] = f2bf(part[tl][ct][r2][li] + bq[hd]);
      vk[j] = f2bf(part[tl][4 + ct][r2][li] + bk[hd]);
    }
    size_t chunk = ((size_t)(b_ * 256 + tgl) * 2 + kh) * 512 + ln * 8;
    *(bf16x8*)(Qf + chunk) = vq;
    *(bf16x8*)(Kf + chunk) = vk;
  }
  // Vf fragment-packed: thread = (ht, lane)
  {
    int ht  = tid >> 6;
    int ln  = tid & 63;
    int gg  = ln >> 4;
    int mi2 = ln & 15;
    int c32 = srb >> 5;
    float bias = bv[ht * 16 + mi2];
    bf16x8 vvv;
#pragma unroll
    for (int hl = 0; hl < 2; ++hl)
#pragma unroll
      for (int j = 0; j < 4; ++j)
        vvv[hl * 4 + j] = f2bf(part[hl][8 + ht][j][gg * 16 + mi2] + bias);
    size_t chunk = ((size_t)(b_ * 128 + c32) * 4 + ht) * 512 + ln * 8;
    *(bf16x8*)(Vf + chunk) = vvv;
  }
}

// ---------------------------------------------------------------------------
// Flash attention: as R7 plus software-pipelined K prefetch (named kA/kB
// buffers, 2x-unrolled loop) so K's L2 latency hides under softmax+PV of the
// previous block.
// ---------------------------------------------------------------------------
struct KFrag { bf16x8 a[4]; bf16x8 b[4]; };

#define LOADK(dst, bb_, bn_) {                                                  \
  const short* kp_ = Kf + ((size_t)((bb_) * 256 + 4 * (bn_)) * 2) * 512 + lane * 8; \
  _Pragma("unroll")                                                             \
  for (int c_ = 0; c_ < 4; ++c_) {                                              \
    dst.a[c_] = *(const bf16x8*)(kp_ + (c_ * 2) * 512);                         \
    dst.b[c_] = *(const bf16x8*)(kp_ + (c_ * 2 + 1) * 512);                     \
  }                                                                             \
}

#define ATTN_BODY(KF, bcur) {                                                   \
  int kv0 = (bcur) * 64;                                                        \
  const short* vp = Vf + ((size_t)(bb * 128 + 2 * (bcur)) * 4) * 512 + lane * 8;\
  bf16x8 vv[8];                                                                 \
  _Pragma("unroll")                                                             \
  for (int i = 0; i < 8; ++i) vv[i] = *(const bf16x8*)(vp + i * 512);           \
  f32x4 z[4];                                                                   \
  __builtin_amdgcn_s_setprio(1);                                                \
  _Pragma("unroll")                                                             \
  for (int c = 0; c < 4; ++c) {                                                 \
    f32x4 zz = (f32x4){0.f, 0.f, 0.f, 0.f};                                     \
    zz = __builtin_amdgcn_mfma_f32_16x16x32_bf16(KF.a[c], qf0, zz, 0, 0, 0);    \
    zz = __builtin_amdgcn_mfma_f32_16x16x32_bf16(KF.b[c], qf1, zz, 0, 0, 0);    \
    z[c] = zz;                                                                  \
  }                                                                             \
  __builtin_amdgcn_s_setprio(0);                                                \
  if (kv0 + 63 > q0) {                                                          \
    _Pragma("unroll")                                                           \
    for (int c = 0; c < 4; ++c)                                                 \
      _Pragma("unroll")                                                         \
      for (int r = 0; r < 4; ++r) {                                             \
        int col = kv0 + c * 16 + 4 * g + r;                                     \
        z[c][r] = (col <= row) ? z[c][r] : -INFINITY;                           \
      }                                                                         \
  }                                                                             \
  float l1 = max3f(z[0][0], z[0][1], z[0][2]);                                  \
  float l2 = max3f(z[0][3], z[1][0], z[1][1]);                                  \
  float l3 = max3f(z[1][2], z[1][3], z[2][0]);                                  \
  float l4 = max3f(z[2][1], z[2][2], z[2][3]);                                  \
  float l5 = max3f(z[3][0], z[3][1], z[3][2]);                                  \
  float lmax = fmaxf(max3f(l1, l2, l3), max3f(l4, l5, z[3][3]));                \
  bool grow = __any(fmaf(lmax, K1, -8.0f) > m2);                                \
  if (grow) {                                                                   \
    float gm = fmaxf(lmax, __shfl_xor(lmax, 16));                               \
    gm = fmaxf(gm, __shfl_xor(gm, 32));                                         \
    float m2n = fmaxf(m2, gm * K1);                                             \
    float alpha = EXP2(m2 - m2n);                                               \
    m2 = m2n;                                                                   \
    lsum *= alpha;                                                              \
    _Pragma("unroll")                                                           \
    for (int i = 0; i < 4; ++i) {                                               \
      o[i][0] *= alpha; o[i][1] *= alpha; o[i][2] *= alpha; o[i][3] *= alpha;   \
    }                                                                           \
  }                                                                             \
  float ls = 0.f;                                                               \
  bf16x4 pb[4];                                                                 \
  _Pragma("unroll")                                                             \
  for (int c = 0; c < 4; ++c) {                                                 \
    float p0 = EXP2(fmaf(z[c][0], K1, -m2));                                    \
    float p1 = EXP2(fmaf(z[c][1], K1, -m2));                                    \
    float p2 = EXP2(fmaf(z[c][2], K1, -m2));                                    \
    float p3 = EXP2(fmaf(z[c][3], K1, -m2));                                    \
    ls += (p0 + p1) + (p2 + p3);                                                \
    pb[c] = pack4(cvtpk(p0, p1), cvtpk(p2, p3));                                \
  }                                                                             \
  lsum += ls;                                                                   \
  __builtin_amdgcn_s_setprio(1);                                                \
  _Pragma("unroll")                                                             \
  for (int c = 0; c < 4; ++c) {                                                 \
    int h2 = c >> 1;                                                            \
    _Pragma("unroll")                                                           \
    for (int ht = 0; ht < 4; ++ht) {                                            \
      bf16x8 vfull = vv[h2 * 4 + ht];                                           \
      bf16x4 va = (c & 1) ? __builtin_shufflevector(vfull, vfull, 4, 5, 6, 7)   \
                          : __builtin_shufflevector(vfull, vfull, 0, 1, 2, 3);  \
      o[ht] = MFMA16(va, pb[c], o[ht]);                                         \
    }                                                                           \
  }                                                                             \
  __builtin_amdgcn_s_setprio(0);                                                \
}

__global__ __launch_bounds__(512, 4) void attn_kernel(
    const short* __restrict__ Qf, const short* __restrict__ Kf,
    const short* __restrict__ Vf, float* __restrict__ out) {
  __shared__ short lds_o[8][64][17];
  __shared__ float lds_m[8][16];
  __shared__ float lds_l[8][16];

  int tid  = threadIdx.x;
  int w    = tid >> 6;
  int lane = tid & 63;
  int g    = lane >> 4;
  int qi   = lane & 15;

  int bid = blockIdx.x;
  int bb  = bid & 3;
  int jj  = (bid >> 3) + (((bid >> 2) & 1) << 6);

  const float K1 = 0.125f * LOG2E;

  for (int ph = 0; ph < 2; ++ph) {
    int t  = ph ? (255 - jj) : jj;
    int q0 = t * 16;
    int row = q0 + qi;

    const short* qp = Qf + ((size_t)(bb * 256 + t) * 2) * 512 + lane * 8;
    bf16x8 qf0 = *(const bf16x8*)(qp);
    bf16x8 qf1 = *(const bf16x8*)(qp + 512);

    int total64 = (t + 4) >> 2;
    int blo = (w * total64) >> 3;
    int bhi = ((w + 1) * total64) >> 3;

    float m2 = -INFINITY, lsum = 0.f;
    f32x4 o[4];
#pragma unroll
    for (int i = 0; i < 4; ++i) o[i] = (f32x4){0.f, 0.f, 0.f, 0.f};

    // software-pipelined main loop: prefetch K(b+1) into the alternate
    // named buffer while processing b (rule #20: static names, no arrays)
    KFrag kA, kB;
    int b = blo;
    if (b < bhi) LOADK(kA, bb, b);
    while (b < bhi) {
      if (b + 1 < bhi) LOADK(kB, bb, b + 1);
      ATTN_BODY(kA, b);
      ++b;
      if (b >= bhi) break;
      if (b + 1 < bhi) LOADK(kA, bb, b + 1);
      ATTN_BODY(kB, b);
      ++b;
    }

    lsum += __shfl_xor(lsum, 16);
    lsum += __shfl_xor(lsum, 32);
#pragma unroll
    for (int ht = 0; ht < 4; ++ht)
#pragma unroll
      for (int r = 0; r < 4; ++r)
        lds_o[w][ht * 16 + 4 * g + r][qi] = f2bf(o[ht][r]);
    if (lane < 16) { lds_m[w][lane] = m2; lds_l[w][lane] = lsum; }
    __syncthreads();

    {
      int q  = tid >> 5;
      int c2 = tid & 31;
      int hb = c2 * 2;
      float mm = lds_m[0][q];
#pragma unroll
      for (int wv = 1; wv < 8; ++wv) mm = fmaxf(mm, lds_m[wv][q]);
      float denom = 0.f, a0 = 0.f, a1 = 0.f;
#pragma unroll
      for (int wv = 0; wv < 8; ++wv) {
        float e = EXP2(lds_m[wv][q] - mm);
        denom += lds_l[wv][q] * e;
        a0 += e * bf2f(lds_o[wv][hb][q]);
        a1 += e * bf2f(lds_o[wv][hb + 1][q]);
      }
      float inv = 1.f / denom;
      float2 res = make_float2(a0 * inv, a1 * inv);
      *(float2*)(out + ((size_t)(bb * SEQ + q0 + q)) * HD + hb) = res;
    }
    __syncthreads();
  }
}

// ---------------------------------------------------------------------------
extern "C" void kernel_launch(void* const* d_in, const int* in_sizes, int n_in,
                              void* d_out, int out_size, void* d_ws, size_t ws_size,
                              hipStream_t stream) {
  const float* X  = (const float*)d_in[0];
  const float* Wq = (const float*)d_in[1];
  const float* bq = (const float*)d_in[2];
  const float* Wk = (const float*)d_in[3];
  const float* bk = (const float*)d_in[4];
  const float* Wv = (const float*)d_in[5];
  const float* bv = (const float*)d_in[6];
  float* out = (float*)d_out;

  char* ws = (char*)d_ws;
  const size_t SZ = (size_t)NROW * HD * 2;
  short* Qf  = (short*)(ws);
  short* Kf  = (short*)(ws + SZ);
  short* Vf  = (short*)(ws + 2 * SZ);
  short* Wtf = (short*)(ws + 3 * SZ);

  wt_kernel<<<48, 256, 0, stream>>>(Wq, Wk, Wv, Wtf);
  qkv_kernel<<<NROW / 32, 256, 0, stream>>>(X, Wtf, bq, bk, bv, Qf, Kf, Vf);
  attn_kernel<<<BATCH * 128, 512, 0, stream>>>(Qf, Kf, Vf, out);
}

// Round 10
// 56.291 us; speedup vs baseline: 3.4489x; 3.4489x over previous
//
#include <hip/hip_runtime.h>

#define BATCH 4
#define SEQ   4096
#define EMB   1024
#define HD    64
#define NROW  (BATCH*SEQ)

typedef float f32x4  __attribute__((ext_vector_type(4)));
typedef short bf16x8 __attribute__((ext_vector_type(8)));
typedef short bf16x4 __attribute__((ext_vector_type(4)));

#define LOG2E 1.4426950408889634f
#define EXP2(x) exp2f(x)

static __device__ __forceinline__ f32x4 MFMA16(bf16x4 a, bf16x4 b, f32x4 c) {
#if defined(__HIP_DEVICE_COMPILE__) && __has_builtin(__builtin_amdgcn_mfma_f32_16x16x16bf16_1k)
  return __builtin_amdgcn_mfma_f32_16x16x16bf16_1k(a, b, c, 0, 0, 0);
#elif defined(__HIP_DEVICE_COMPILE__)
  f32x4 d;
  asm volatile("v_mfma_f32_16x16x16_bf16 %0, %1, %2, %3"
               : "=v"(d) : "v"(a), "v"(b), "v"(c));
  return d;
#else
  return c;  // host stub, never executed
#endif
}

static __device__ __forceinline__ short f2bf(float f) {
  union { float f; unsigned u; } v; v.f = f;
  unsigned r = v.u + 0x7fffu + ((v.u >> 16) & 1u);
  return (short)(r >> 16);
}
static __device__ __forceinline__ float bf2f(short s) {
  union { unsigned u; float f; } v; v.u = ((unsigned)(unsigned short)s) << 16;
  return v.f;
}
static __device__ __forceinline__ unsigned cvtpk(float lo, float hi) {
  unsigned r;
  asm("v_cvt_pk_bf16_f32 %0, %1, %2" : "=v"(r) : "v"(lo), "v"(hi));
  return r;
}
static __device__ __forceinline__ float max3f(float a, float b, float c) {
  float r;
  asm("v_max3_f32 %0, %1, %2, %3" : "=v"(r) : "v"(a), "v"(b), "v"(c));
  return r;
}
static __device__ __forceinline__ bf16x4 pack4(unsigned w01, unsigned w23) {
  union { unsigned u[2]; bf16x4 v; } x;
  x.u[0] = w01; x.u[1] = w23;
  return x.v;
}

// ---------------------------------------------------------------------------
// Wtf: fragment-contiguous B layout (unchanged).
// ---------------------------------------------------------------------------
__global__ __launch_bounds__(256) void wt_kernel(
    const float* __restrict__ Wq, const float* __restrict__ Wk,
    const float* __restrict__ Wv, short* __restrict__ Wtf) {
  __shared__ float t[64][65];
  int bid = blockIdx.x;
  int mat = bid >> 4;
  int et  = bid & 15;
  int e0  = et * 64;
  const float* W = (mat == 0) ? Wq : (mat == 1) ? Wk : Wv;
  int c  = threadIdx.x & 63;
  int r0 = threadIdx.x >> 6;
#pragma unroll
  for (int i = 0; i < 16; ++i)
    t[i * 4 + r0][c] = W[(size_t)(e0 + i * 4 + r0) * HD + c];
  __syncthreads();
#pragma unroll
  for (int half = 0; half < 2; ++half) {
    int cid  = half * 256 + threadIdx.x;
    int ct4  = cid >> 7;
    int ksl  = (cid >> 6) & 1;
    int lane = cid & 63;
    int g    = lane >> 4;
    int mi   = lane & 15;
    int ct   = mat * 4 + ct4;
    int ks   = et * 2 + ksl;
    bf16x8 v;
#pragma unroll
    for (int j = 0; j < 8; ++j)
      v[j] = f2bf(t[ksl * 32 + 8 * g + j][ct4 * 16 + mi]);
    *(bf16x8*)(Wtf + ((size_t)(ct * 32 + ks) * 64 + lane) * 8) = v;
  }
}

// ---------------------------------------------------------------------------
// QKV projection (known-good R7 version: BM=32, split-K x2, dbuf LDS).
// ---------------------------------------------------------------------------
__global__ __launch_bounds__(256) void qkv_kernel(
    const float* __restrict__ X, const short* __restrict__ Wtf,
    const float* __restrict__ bq, const float* __restrict__ bk, const float* __restrict__ bv,
    short* __restrict__ Qf, short* __restrict__ Kf, short* __restrict__ Vf) {
  __shared__ __align__(16) short xs[2][2][32][32];
  __shared__ float part[2][12][4][64];

  int tid  = threadIdx.x;
  int w    = tid >> 6;
  int lane = tid & 63;
  int g    = lane >> 4;
  int mi   = lane & 15;
  int rs   = w & 1;
  int h    = w >> 1;
  int rowbase = blockIdx.x * 32;

  int sr = tid >> 3;
  int sc = tid & 7;
  const float* xsrc = X + (size_t)(rowbase + sr) * EMB + sc * 4;

  f32x4 acc[12];
#pragma unroll
  for (int i = 0; i < 12; ++i) acc[i] = (f32x4){0.f, 0.f, 0.f, 0.f};

  {
    float4 xa = *(const float4*)(xsrc);
    float4 xb = *(const float4*)(xsrc + 512);
    bf16x4 va, vb;
    va[0] = f2bf(xa.x); va[1] = f2bf(xa.y); va[2] = f2bf(xa.z); va[3] = f2bf(xa.w);
    vb[0] = f2bf(xb.x); vb[1] = f2bf(xb.y); vb[2] = f2bf(xb.z); vb[3] = f2bf(xb.w);
    *(bf16x4*)(&xs[0][0][sr][sc * 4]) = va;
    *(bf16x4*)(&xs[0][1][sr][sc * 4]) = vb;
  }
  __syncthreads();

  const short* wp = Wtf + (size_t)(h * 16) * 512 + lane * 8;

#pragma unroll 2
  for (int ks = 0; ks < 16; ++ks) {
    int buf = ks & 1;
    float4 xa, xb;
    if (ks < 15) {
      xa = *(const float4*)(xsrc + (ks + 1) * 32);
      xb = *(const float4*)(xsrc + (ks + 1) * 32 + 512);
    }
    bf16x8 af = *(const bf16x8*)(&xs[buf][h][rs * 16 + mi][g * 8]);
    const short* wk = wp + ks * 512;
#pragma unroll
    for (int ct = 0; ct < 12; ++ct) {
      bf16x8 bfr = *(const bf16x8*)(wk + (size_t)ct * 16384);
      acc[ct] = __builtin_amdgcn_mfma_f32_16x16x32_bf16(af, bfr, acc[ct], 0, 0, 0);
    }
    if (ks < 15) {
      bf16x4 va, vb;
      va[0] = f2bf(xa.x); va[1] = f2bf(xa.y); va[2] = f2bf(xa.z); va[3] = f2bf(xa.w);
      vb[0] = f2bf(xb.x); vb[1] = f2bf(xb.y); vb[2] = f2bf(xb.z); vb[3] = f2bf(xb.w);
      *(bf16x4*)(&xs[buf ^ 1][0][sr][sc * 4]) = va;
      *(bf16x4*)(&xs[buf ^ 1][1][sr][sc * 4]) = vb;
    }
    __syncthreads();
  }

  if (h == 1) {
#pragma unroll
    for (int ct = 0; ct < 12; ++ct)
#pragma unroll
      for (int r = 0; r < 4; ++r) part[rs][ct][r][lane] = acc[ct][r];
  }
  __syncthreads();
  if (h == 0) {
#pragma unroll
    for (int ct = 0; ct < 12; ++ct)
#pragma unroll
      for (int r = 0; r < 4; ++r) part[rs][ct][r][lane] += acc[ct][r];
  }
  __syncthreads();

  int b_  = rowbase >> 12;                 // batch
  int srb = rowbase & (SEQ - 1);           // row within batch

  {
    int tl  = tid >> 7;
    int kh  = (tid >> 6) & 1;
    int ln  = tid & 63;
    int gg  = ln >> 4;
    int mi2 = ln & 15;
    int tgl = (srb >> 4) + tl;
    bf16x8 vq, vk;
#pragma unroll
    for (int j = 0; j < 8; ++j) {
      int hd = kh * 32 + 8 * gg + j;
      int ct = hd >> 4, cc = hd & 15;
      int li = (mi2 >> 2) * 16 + cc;
      int r2 = mi2 & 3;
      vq[j] = f2bf(part[tl][ct][r2][li] + bq[hd]);
      vk[j] = f2bf(part[tl][4 + ct][r2][li] + bk[hd]);
    }
    size_t chunk = ((size_t)(b_ * 256 + tgl) * 2 + kh) * 512 + ln * 8;
    *(bf16x8*)(Qf + chunk) = vq;
    *(bf16x8*)(Kf + chunk) = vk;
  }
  {
    int ht  = tid >> 6;
    int ln  = tid & 63;
    int gg  = ln >> 4;
    int mi2 = ln & 15;
    int c32 = srb >> 5;
    float bias = bv[ht * 16 + mi2];
    bf16x8 vvv;
#pragma unroll
    for (int hl = 0; hl < 2; ++hl)
#pragma unroll
      for (int j = 0; j < 4; ++j)
        vvv[hl * 4 + j] = f2bf(part[hl][8 + ht][j][gg * 16 + mi2] + bias);
    size_t chunk = ((size_t)(b_ * 128 + c32) * 4 + ht) * 512 + ln * 8;
    *(bf16x8*)(Vf + chunk) = vvv;
  }
}

// ---------------------------------------------------------------------------
// Flash attention: 2 q-tiles (32 rows) per wave share each K/V fragment read
// -> L2 traffic per q-row halved. Block = 8 waves on tiles {2G, 2G+1}, kv
// split 8-way, pair (G, 127-G). grid 256. launch_bounds (512,2): 256-VGPR
// budget, no spills. All per-tile loops fully unrolled (static indexing).
// ---------------------------------------------------------------------------
__global__ __launch_bounds__(512, 2) void attn_kernel(
    const short* __restrict__ Qf, const short* __restrict__ Kf,
    const short* __restrict__ Vf, float* __restrict__ out) {
  __shared__ short lds_o[8][2][64][17];
  __shared__ float lds_m[8][2][16];
  __shared__ float lds_l[8][2][16];

  int tid  = threadIdx.x;
  int w    = tid >> 6;
  int lane = tid & 63;
  int g    = lane >> 4;
  int qi   = lane & 15;

  int bid = blockIdx.x;
  int bb  = bid & 3;          // batch pinned per XCD pair
  int j   = bid >> 2;         // 0..63

  const float K1 = 0.125f * LOG2E;

  for (int ph = 0; ph < 2; ++ph) {
    int G  = ph ? (127 - j) : j;     // 32-row group index, 0..127
    int q0 = G * 32;

    bf16x8 qf0[2], qf1[2];
#pragma unroll
    for (int tl = 0; tl < 2; ++tl) {
      const short* qp = Qf + ((size_t)(bb * 256 + 2 * G + tl) * 2) * 512 + lane * 8;
      qf0[tl] = *(const bf16x8*)(qp);
      qf1[tl] = *(const bf16x8*)(qp + 512);
    }

    int total64 = (G + 2) >> 1;      // 64-kv blocks covering tile B's range
    int blo = (w * total64) >> 3;
    int bhi = ((w + 1) * total64) >> 3;

    float m2[2]   = {-INFINITY, -INFINITY};
    float lsum[2] = {0.f, 0.f};
    f32x4 o[2][4];
#pragma unroll
    for (int tl = 0; tl < 2; ++tl)
#pragma unroll
      for (int i = 0; i < 4; ++i) o[tl][i] = (f32x4){0.f, 0.f, 0.f, 0.f};

    for (int b = blo; b < bhi; ++b) {
      int kv0 = b * 64;
      const short* kp = Kf + ((size_t)(bb * 256 + 4 * b) * 2) * 512 + lane * 8;
      const short* vp = Vf + ((size_t)(bb * 128 + 2 * b) * 4) * 512 + lane * 8;

      bf16x8 kfa[4], kfb[4];
#pragma unroll
      for (int c = 0; c < 4; ++c) {
        kfa[c] = *(const bf16x8*)(kp + (c * 2) * 512);
        kfb[c] = *(const bf16x8*)(kp + (c * 2 + 1) * 512);
      }
      bf16x8 vv[8];
#pragma unroll
      for (int i = 0; i < 8; ++i) vv[i] = *(const bf16x8*)(vp + i * 512);

      // ---- QK^T for both tiles (K fragments shared) ----
      f32x4 z[2][4];
      __builtin_amdgcn_s_setprio(1);
#pragma unroll
      for (int tl = 0; tl < 2; ++tl)
#pragma unroll
        for (int c = 0; c < 4; ++c) {
          f32x4 zz = (f32x4){0.f, 0.f, 0.f, 0.f};
          zz = __builtin_amdgcn_mfma_f32_16x16x32_bf16(kfa[c], qf0[tl], zz, 0, 0, 0);
          zz = __builtin_amdgcn_mfma_f32_16x16x32_bf16(kfb[c], qf1[tl], zz, 0, 0, 0);
          z[tl][c] = zz;
        }
      __builtin_amdgcn_s_setprio(0);

      if (kv0 + 63 > q0) {             // only diagonal-adjacent blocks
#pragma unroll
        for (int tl = 0; tl < 2; ++tl) {
          int rowt = q0 + tl * 16 + qi;
#pragma unroll
          for (int c = 0; c < 4; ++c)
#pragma unroll
            for (int r = 0; r < 4; ++r) {
              int col = kv0 + c * 16 + 4 * g + r;
              z[tl][c][r] = (col <= rowt) ? z[tl][c][r] : -INFINITY;
            }
        }
      }

      // ---- softmax per tile (defer-max THR=8) ----
      bf16x4 pb[2][4];
#pragma unroll
      for (int tl = 0; tl < 2; ++tl) {
        float l1 = max3f(z[tl][0][0], z[tl][0][1], z[tl][0][2]);
        float l2 = max3f(z[tl][0][3], z[tl][1][0], z[tl][1][1]);
        float l3 = max3f(z[tl][1][2], z[tl][1][3], z[tl][2][0]);
        float l4 = max3f(z[tl][2][1], z[tl][2][2], z[tl][2][3]);
        float l5 = max3f(z[tl][3][0], z[tl][3][1], z[tl][3][2]);
        float lmax = fmaxf(max3f(l1, l2, l3), max3f(l4, l5, z[tl][3][3]));
        bool grow = __any(fmaf(lmax, K1, -8.0f) > m2[tl]);
        if (grow) {
          float gm = fmaxf(lmax, __shfl_xor(lmax, 16));
          gm = fmaxf(gm, __shfl_xor(gm, 32));
          float m2n = fmaxf(m2[tl], gm * K1);
          float alpha = EXP2(m2[tl] - m2n);
          m2[tl] = m2n;
          lsum[tl] *= alpha;
#pragma unroll
          for (int i = 0; i < 4; ++i) {
            o[tl][i][0] *= alpha; o[tl][i][1] *= alpha;
            o[tl][i][2] *= alpha; o[tl][i][3] *= alpha;
          }
        }
        float ls = 0.f;
#pragma unroll
        for (int c = 0; c < 4; ++c) {
          float p0 = EXP2(fmaf(z[tl][c][0], K1, -m2[tl]));
          float p1 = EXP2(fmaf(z[tl][c][1], K1, -m2[tl]));
          float p2 = EXP2(fmaf(z[tl][c][2], K1, -m2[tl]));
          float p3 = EXP2(fmaf(z[tl][c][3], K1, -m2[tl]));
          ls += (p0 + p1) + (p2 + p3);
          pb[tl][c] = pack4(cvtpk(p0, p1), cvtpk(p2, p3));
        }
        lsum[tl] += ls;
      }

      // ---- PV for both tiles (V fragments shared) ----
      __builtin_amdgcn_s_setprio(1);
#pragma unroll
      for (int tl = 0; tl < 2; ++tl)
#pragma unroll
        for (int c = 0; c < 4; ++c) {
          int h2 = c >> 1;
#pragma unroll
          for (int ht = 0; ht < 4; ++ht) {
            bf16x8 vfull = vv[h2 * 4 + ht];
            bf16x4 va = (c & 1) ? __builtin_shufflevector(vfull, vfull, 4, 5, 6, 7)
                                : __builtin_shufflevector(vfull, vfull, 0, 1, 2, 3);
            o[tl][ht] = MFMA16(va, pb[tl][c], o[tl][ht]);
          }
        }
      __builtin_amdgcn_s_setprio(0);
    }

    // ---- cross-wave flash combine, both tiles ----
#pragma unroll
    for (int tl = 0; tl < 2; ++tl) {
      float ls = lsum[tl];
      ls += __shfl_xor(ls, 16);
      ls += __shfl_xor(ls, 32);
#pragma unroll
      for (int ht = 0; ht < 4; ++ht)
#pragma unroll
        for (int r = 0; r < 4; ++r)
          lds_o[w][tl][ht * 16 + 4 * g + r][qi] = f2bf(o[tl][ht][r]);
      if (lane < 16) { lds_m[w][tl][lane] = m2[tl]; lds_l[w][tl][lane] = ls; }
    }
    __syncthreads();

#pragma unroll
    for (int tl = 0; tl < 2; ++tl) {
      int q  = tid >> 5;
      int c2 = tid & 31;
      int hb = c2 * 2;
      float mm = lds_m[0][tl][q];
#pragma unroll
      for (int wv = 1; wv < 8; ++wv) mm = fmaxf(mm, lds_m[wv][tl][q]);
      float denom = 0.f, a0 = 0.f, a1 = 0.f;
#pragma unroll
      for (int wv = 0; wv < 8; ++wv) {
        float e = EXP2(lds_m[wv][tl][q] - mm);
        denom += lds_l[wv][tl][q] * e;
        a0 += e * bf2f(lds_o[wv][tl][hb][q]);
        a1 += e * bf2f(lds_o[wv][tl][hb + 1][q]);
      }
      float inv = 1.f / denom;
      float2 res = make_float2(a0 * inv, a1 * inv);
      *(float2*)(out + ((size_t)(bb * SEQ + q0 + tl * 16 + q)) * HD + hb) = res;
    }
    __syncthreads();
  }
}

// ---------------------------------------------------------------------------
extern "C" void kernel_launch(void* const* d_in, const int* in_sizes, int n_in,
                              void* d_out, int out_size, void* d_ws, size_t ws_size,
                              hipStream_t stream) {
  const float* X  = (const float*)d_in[0];
  const float* Wq = (const float*)d_in[1];
  const float* bq = (const float*)d_in[2];
  const float* Wk = (const float*)d_in[3];
  const float* bk = (const float*)d_in[4];
  const float* Wv = (const float*)d_in[5];
  const float* bv = (const float*)d_in[6];
  float* out = (float*)d_out;

  char* ws = (char*)d_ws;
  const size_t SZ = (size_t)NROW * HD * 2;
  short* Qf  = (short*)(ws);
  short* Kf  = (short*)(ws + SZ);
  short* Vf  = (short*)(ws + 2 * SZ);
  short* Wtf = (short*)(ws + 3 * SZ);

  wt_kernel<<<48, 256, 0, stream>>>(Wq, Wk, Wv, Wtf);
  qkv_kernel<<<NROW / 32, 256, 0, stream>>>(X, Wtf, bq, bk, bv, Qf, Kf, Vf);
  attn_kernel<<<256, 512, 0, stream>>>(Qf, Kf, Vf, out);
}